// Round 5
// baseline (511.044 us; speedup 1.0000x reference)
//
#include <hip/hip_runtime.h>
#include <math.h>

#define DD 128
#define CAP 32
constexpr float EPS = 1e-5f;

typedef __bf16 bf16x8 __attribute__((ext_vector_type(8)));
typedef float  f32x4  __attribute__((ext_vector_type(4)));

__device__ __forceinline__ float4 ld4(const float* p){ return *(const float4*)p; }

__device__ __forceinline__ bf16x8 cvt8(const float* p){
  bf16x8 r;
#pragma unroll
  for (int i=0;i<8;i++) r[i] = (__bf16)p[i];
  return r;
}

// ---------- weight pre-pack: B-frag-major bf16 ----------
__global__ __launch_bounds__(256)
void pack_w(const float* W0, const float* W1, const float* W2, const float* W3,
            const float* W4, const float* W5, const float* W6, const float* W7,
            __bf16* dst){
  int gidx = blockIdx.x*256 + threadIdx.x;
  int mat  = gidx >> 11;
  int i    = gidx & 2047;
  int lane = i & 63, frag = i >> 6;          // frag = tn*4+ks
  int tn = frag >> 2, ks = frag & 3;
  int n  = tn*16 + (lane & 15);
  int k0 = ks*32 + (lane >> 4)*8;
  const float* W;
  switch(mat){
    case 0: W=W0; break; case 1: W=W1; break; case 2: W=W2; break; case 3: W=W3; break;
    case 4: W=W4; break; case 5: W=W5; break; case 6: W=W6; break; default: W=W7; break;
  }
  __bf16* d = dst + (size_t)mat*16384 + (size_t)i*8;
#pragma unroll
  for (int j=0;j<8;j++) d[j] = (__bf16)W[(size_t)(k0+j)*DD + n];
}

// ---------- GroupNorm(1,128) in MFMA C-frag domain ----------
template<bool RELU>
__device__ __forceinline__ void gn_frag(f32x4 (&acc)[8], const float* __restrict__ g,
                                        const float* __restrict__ b, int m){
  float gv[8], bv[8];
#pragma unroll
  for (int t=0;t<8;t++){ gv[t]=g[t*16+m]; bv[t]=b[t*16+m]; }
#pragma unroll
  for (int r=0;r<4;r++){
    float s=0.f, sq=0.f;
#pragma unroll
    for (int t=0;t<8;t++){ float v=acc[t][r]; s+=v; sq=fmaf(v,v,sq); }
#pragma unroll
    for (int mk=1; mk<16; mk<<=1){ s+=__shfl_xor(s,mk,64); sq+=__shfl_xor(sq,mk,64); }
    float mu=s*(1.f/DD);
    float rs=rsqrtf(sq*(1.f/DD)-mu*mu+EPS);
#pragma unroll
    for (int t=0;t<8;t++){
      float v=(acc[t][r]-mu)*rs*gv[t]+bv[t];
      if (RELU) v=fmaxf(v,0.f);
      acc[t][r]=v;
    }
  }
}

// ---------- MFMA: acc = A_frags @ WL (LDS-staged weights) ----------
__device__ __forceinline__ void mfma_lds(const bf16x8 (&af)[4], const __bf16* WL,
                                         f32x4 (&acc)[8], int lane){
#pragma unroll
  for (int tn=0;tn<8;tn++){
    f32x4 a; a[0]=0.f; a[1]=0.f; a[2]=0.f; a[3]=0.f;
#pragma unroll
    for (int ks=0;ks<4;ks++){
      bf16x8 bf = *(const bf16x8*)(WL + ((tn*4+ks)*64 + lane)*8);
      a = __builtin_amdgcn_mfma_f32_16x16x32_bf16(af[ks], bf, a, 0,0,0);
    }
    acc[tn]=a;
  }
}

// ---------- MFMA, two row-tiles per wave: weight frag loaded once, used twice ----------
__device__ __forceinline__ void mfma_lds2(const bf16x8 (&af0)[4], const bf16x8 (&af1)[4],
                                          const __bf16* WL,
                                          f32x4 (&acc0)[8], f32x4 (&acc1)[8], int lane){
#pragma unroll
  for (int tn=0;tn<8;tn++){
    f32x4 a0; a0[0]=0.f; a0[1]=0.f; a0[2]=0.f; a0[3]=0.f;
    f32x4 a1; a1[0]=0.f; a1[1]=0.f; a1[2]=0.f; a1[3]=0.f;
#pragma unroll
    for (int ks=0;ks<4;ks++){
      bf16x8 bf = *(const bf16x8*)(WL + ((tn*4+ks)*64 + lane)*8);
      a0 = __builtin_amdgcn_mfma_f32_16x16x32_bf16(af0[ks], bf, a0, 0,0,0);
      a1 = __builtin_amdgcn_mfma_f32_16x16x32_bf16(af1[ks], bf, a1, 0,0,0);
    }
    acc0[tn]=a0; acc1[tn]=a1;
  }
}

// ---------- async stage one packed 32KB weight matrix into LDS (4 waves) ----------
__device__ __forceinline__ void stage_w(const __bf16* __restrict__ Wg, __bf16* WL, int w, int lane){
#pragma unroll
  for (int j=0;j<8;j++){
    int off = ((w*8+j)<<10) + lane*16;   // bytes
    __builtin_amdgcn_global_load_lds(
      (const __attribute__((address_space(1))) void*)((const char*)Wg + off),
      (__attribute__((address_space(3))) void*)((char*)WL + ((w*8+j)<<10)),
      16, 0, 0);
  }
}

__device__ __forceinline__ void read_af(const __bf16* T, bf16x8 (&af)[4], int w, int lane){
  int m=lane&15, q=lane>>4;
#pragma unroll
  for (int ks=0;ks<4;ks++)
    af[ks] = *(const bf16x8*)(T + (16*w+m)*136 + ks*32 + q*8);
}

// two row-tiles (rows rb+m and rb+16+m)
__device__ __forceinline__ void read_af2(const __bf16* T, bf16x8 (&af0)[4], bf16x8 (&af1)[4],
                                         int rb, int lane){
  int m=lane&15, q=lane>>4;
#pragma unroll
  for (int ks=0;ks<4;ks++){
    af0[ks] = *(const bf16x8*)(T + (rb+m)*136    + ks*32 + q*8);
    af1[ks] = *(const bf16x8*)(T + (rb+16+m)*136 + ks*32 + q*8);
  }
}

__device__ __forceinline__ void write_cfrag_bf16(__bf16* T, const f32x4 (&acc)[8], int w, int lane){
  int m=lane&15, q=lane>>4;
#pragma unroll
  for (int r=0;r<4;r++){
    int row=16*w+4*q+r;
#pragma unroll
    for (int t=0;t<8;t++) T[row*136 + t*16 + m] = (__bf16)acc[t][r];
  }
}

__device__ __forceinline__ void write_cfrag2(__bf16* T, const f32x4 (&acc0)[8], const f32x4 (&acc1)[8],
                                             int rb, int lane){
  int m=lane&15, q=lane>>4;
#pragma unroll
  for (int r=0;r<4;r++){
    int row0=rb+4*q+r, row1=rb+16+4*q+r;
#pragma unroll
    for (int t=0;t<8;t++){
      T[row0*136 + t*16 + m] = (__bf16)acc0[t][r];
      T[row1*136 + t*16 + m] = (__bf16)acc1[t][r];
    }
  }
}

__device__ __forceinline__ void load_af_f32(const float* X, bf16x8 (&af)[4], int row, int M, int q){
  if (row < M){
    const float* xr = X + (size_t)row*DD;
#pragma unroll
    for (int ks=0;ks<4;ks++){
      float t[8];
      *(float4*)t     = ld4(xr + ks*32 + q*8);
      *(float4*)(t+4) = ld4(xr + ks*32 + q*8 + 4);
      af[ks] = cvt8(t);
    }
  } else {
#pragma unroll
    for (int ks=0;ks<4;ks++){
#pragma unroll
      for (int j=0;j<8;j++) af[ks][j]=(__bf16)0.f;
    }
  }
}

// ---------- prep: [bucket build] + [Q->Aq2 (+base)] + [Cc], LDS-staged weights ----------
__global__ __launch_bounds__(256)
void prep_kernel(const int* __restrict__ hi, int E, int* __restrict__ counts, int* __restrict__ perm,
                 const float* __restrict__ agts,
                 const __bf16* __restrict__ Wp_q, const float* __restrict__ g_q, const float* __restrict__ b_q,
                 const __bf16* __restrict__ Wp_mid, const __bf16* __restrict__ Wp_agt,
                 __bf16* __restrict__ Aq2bf, float* __restrict__ baseF, int nA,
                 const float* __restrict__ ctx, const __bf16* __restrict__ Wp_chi,
                 __bf16* __restrict__ Ccbf, int nC,
                 int gBucket, int gA){
  __shared__ __bf16 T[64*136];
  __shared__ __bf16 WL[16384];
  int b = blockIdx.x;
  if (b < gBucket){
    int e = b*256 + threadIdx.x;
    if (e < E){
      int a = hi[e];
      int slot = atomicAdd(&counts[a], 1);
      if (slot < CAP) perm[(size_t)a*CAP + slot] = e;
    }
    return;
  }
  b -= gBucket;
  int tid=threadIdx.x, w=tid>>6, lane=tid&63, m=lane&15, q=lane>>4;
  if (b < gA){
    stage_w(Wp_q, WL, w, lane);              // issue W_q -> LDS
    int rowA = b*64 + 16*w + m;
    bf16x8 af_a[4];
    load_af_f32(agts, af_a, rowA, nA, q);    // covers staging latency
    f32x4 acc[8];
    __syncthreads();                         // WL(q) landed
    // Q = relu(gn(agts @ W_q)) -> LDS transpose (band-local)
    mfma_lds(af_a, WL, acc, lane);
    __syncthreads();                         // all waves done reading WL(q)
    stage_w(Wp_mid, WL, w, lane);            // issue W_c1mid; hidden by gn+transpose
    gn_frag<true>(acc, g_q, b_q, m);
    write_cfrag_bf16(T, acc, w, lane);
    bf16x8 af_q[4];
    read_af(T, af_q, w, lane);
    __syncthreads();                         // WL(mid) landed
    // Aq2 = Q @ W_c1mid
    mfma_lds(af_q, WL, acc, lane);
#pragma unroll
    for (int r=0;r<4;r++){
      int row = b*64 + 16*w + 4*q + r;
      if (row < nA){
#pragma unroll
        for (int t=0;t<8;t++)
          Aq2bf[(size_t)row*DD + t*16 + m] = (__bf16)acc[t][r];
      }
    }
    if (baseF){
      __syncthreads();                       // all waves done reading WL(mid)
      stage_w(Wp_agt, WL, w, lane);
      __syncthreads();                       // WL(agt) landed
      mfma_lds(af_a, WL, acc, lane);
#pragma unroll
      for (int r=0;r<4;r++){
        int row = b*64 + 16*w + 4*q + r;
        if (row < nA){
#pragma unroll
          for (int t=0;t<8;t++)
            baseF[(size_t)row*DD + t*16 + m] = acc[t][r];
        }
      }
    }
  } else {
    int bid = b - gA;
    stage_w(Wp_chi, WL, w, lane);            // issue W_c1hi -> LDS
    int rowA = bid*64 + 16*w + m;
    bf16x8 af[4];
    load_af_f32(ctx, af, rowA, nC, q);       // covers staging latency
    f32x4 acc[8];
    __syncthreads();                         // WL(chi) landed
    mfma_lds(af, WL, acc, lane);
#pragma unroll
    for (int r=0;r<4;r++){
      int row = bid*64 + 16*w + 4*q + r;
      if (row < nC){
#pragma unroll
        for (int t=0;t<8;t++)
          Ccbf[(size_t)row*DD + t*16 + m] = (__bf16)acc[t][r];
      }
    }
  }
}

// ---------- fused edge kernel: 128 edges/block, 4 waves x 32 rows, LDS-staged weights ----------
// Each wave owns 32 rows (two 16-row MFMA tiles): weight frags read from LDS once per
// (tn,ks) and feed TWO MFMAs -> halves the dominant DS-pipe term.
__global__ __launch_bounds__(256,2)
void edge_kernel(const float* __restrict__ agt_ctrs, const float* __restrict__ ctx_ctrs,
                 const int* __restrict__ hi, const int* __restrict__ wi,
                 const float* __restrict__ W1, const float* __restrict__ B1,
                 const __bf16* __restrict__ Wp_d2, const float* __restrict__ g_dist, const float* __restrict__ b_dist,
                 const __bf16* __restrict__ Wp_c1, const float* __restrict__ g_c1, const float* __restrict__ b_c1,
                 const __bf16* __restrict__ Wp_c2,
                 const __bf16* __restrict__ Aq2, const __bf16* __restrict__ Cc,
                 float* __restrict__ accOut, __bf16* __restrict__ edge_out, int E){
  __shared__ __bf16 T[128*136];     // 34816 B
  __shared__ __bf16 WL[16384];      // 32768 B
  int tid=threadIdx.x, w=tid>>6, lane=tid&63, m=lane&15, q=lane>>4;
  int eBase = blockIdx.x*128;
  int rb = 32*w;                    // wave row base (rows rb..rb+31)
  // ---- gather prefetch: 2 lanes/row, 64 channels each (band-local rows) ----
  int grow = tid>>1, gch = tid&1;   // grow in [rb, rb+31] for this wave
  int ge = eBase + grow;
  int ghe=0, gwe=0;
  if (ge < E){ ghe = hi[ge]; gwe = wi[ge]; }
  bf16x8 ga[8], gc[8];
  {
    const __bf16* ap = Aq2 + (size_t)ghe*DD + gch*64;
    const __bf16* cp = Cc  + (size_t)gwe*DD + gch*64;
#pragma unroll
    for (int c2=0;c2<8;c2++){ ga[c2]=*(const bf16x8*)(ap+c2*8); gc[c2]=*(const bf16x8*)(cp+c2*8); }
  }
  // ---- issue W_dist2 -> LDS (covered by stage0 compute) ----
  stage_w(Wp_d2, WL, w, lane);
  // ---- stage0: d1 = relu(delta @ W_dist1 + b1); 128 rows, each thread 1 row x 64 cols ----
  {
    int e0 = grow, wc = gch*64;
    int e = eBase + e0;
    float dx=0.f, dy=0.f;
    if (e < E){
      int h0=hi[e], w0=wi[e];
      dx = agt_ctrs[2*h0]   - ctx_ctrs[2*w0];
      dy = agt_ctrs[2*h0+1] - ctx_ctrs[2*w0+1];
    }
#pragma unroll
    for (int s=0;s<8;s++){
      float t[8];
#pragma unroll
      for (int j=0;j<8;j++){
        int c = wc + s*8 + j;
        t[j] = fmaxf(fmaf(dx, W1[c], fmaf(dy, W1[DD+c], B1[c])), 0.f);
      }
      *(bf16x8*)(T + e0*136 + wc + s*8) = cvt8(t);
    }
  }
  __syncthreads();                       // T(stage0) ready + WL(d2) landed
  bf16x8 af0[4], af1[4]; f32x4 acc0[8], acc1[8];
  // ---- stage1: d = relu(gn(d1 @ W_dist2)) ----
  read_af2(T, af0, af1, rb, lane);
  mfma_lds2(af0, af1, WL, acc0, acc1, lane);
  __syncthreads();                       // all waves done reading WL(d2)
  stage_w(Wp_c1, WL, w, lane);           // issue W_c1lo; latency hidden by gn + transposes
  gn_frag<true>(acc0, g_dist, b_dist, m);
  gn_frag<true>(acc1, g_dist, b_dist, m);
  write_cfrag2(T, acc0, acc1, rb, lane);
  // ---- stage2 prep: read d into regs, write Aq2[hi]+Cc[wi] sums into T ----
  read_af2(T, af0, af1, rb, lane);
#pragma unroll
  for (int c2=0;c2<8;c2++){
    float s[8];
#pragma unroll
    for (int j=0;j<8;j++) s[j] = (float)ga[c2][j] + (float)gc[c2][j];
    *(bf16x8*)(T + grow*136 + gch*64 + c2*8) = cvt8(s);
  }
  __syncthreads();                       // WL(c1) landed
  // ---- stage2: c = relu(gn(d @ W_c1lo + Aq2[hi] + Cc[wi])) ----
  mfma_lds2(af0, af1, WL, acc0, acc1, lane);
#pragma unroll
  for (int r=0;r<4;r++){
    int row0 = rb + 4*q + r, row1 = rb + 16 + 4*q + r;
#pragma unroll
    for (int t=0;t<8;t++){
      acc0[t][r] += (float)T[row0*136 + t*16 + m];
      acc1[t][r] += (float)T[row1*136 + t*16 + m];
    }
  }
  __syncthreads();                       // all waves done reading WL(c1)
  stage_w(Wp_c2, WL, w, lane);           // issue W_c2; hidden by gn + transposes
  gn_frag<true>(acc0, g_c1, b_c1, m);
  gn_frag<true>(acc1, g_c1, b_c1, m);
  write_cfrag2(T, acc0, acc1, rb, lane);
  read_af2(T, af0, af1, rb, lane);
  __syncthreads();                       // WL(c2) landed
  // ---- stage3: e_out = c @ W_c2 ----
  mfma_lds2(af0, af1, WL, acc0, acc1, lane);
  if (edge_out){
    // streaming bf16 store, row-major via band-local LDS transpose
    write_cfrag2(T, acc0, acc1, rb, lane);
    if (ge < E){
      const __bf16* src = T + grow*136 + gch*64;
      __bf16* dst = edge_out + (size_t)ge*DD + gch*64;
#pragma unroll
      for (int c2=0;c2<8;c2++) *(bf16x8*)(dst + c2*8) = *(const bf16x8*)(src + c2*8);
    }
  } else {
#pragma unroll
    for (int r=0;r<4;r++){
      int row0 = rb + 4*q + r, row1 = rb + 16 + 4*q + r;
      if (eBase + row0 < E){
        int he = hi[eBase + row0];
        float* dst = accOut + (size_t)he*DD + m;
#pragma unroll
        for (int t=0;t<8;t++) atomicAdd(dst + t*16, acc0[t][r]);
      }
      if (eBase + row1 < E){
        int he = hi[eBase + row1];
        float* dst = accOut + (size_t)he*DD + m;
#pragma unroll
        for (int t=0;t<8;t++) atomicAdd(dst + t*16, acc1[t][r]);
      }
    }
  }
}

// ---------- path-A final: base MFMA + edge gather-sum + GN chain + residual ----------
// Weight staging aliased onto Tf (33792B >= 32768B) to keep LDS at 51200.
__global__ __launch_bounds__(256)
void final_fused(const float* __restrict__ agts, const __bf16* __restrict__ Wp_agt,
                 const int* __restrict__ counts, const int* __restrict__ perm,
                 const __bf16* __restrict__ edge_out,
                 const float* __restrict__ g_n, const float* __restrict__ b_n,
                 const __bf16* __restrict__ Wp_lin, const float* __restrict__ g_lin, const float* __restrict__ b_lin,
                 float* __restrict__ out, int M){
  __shared__ float Tf[64*132];           // 33792 B; doubles as weight-staging buffer
  __shared__ __bf16 T[64*136];
  __bf16* WA = (__bf16*)Tf;
  int tid=threadIdx.x, w=tid>>6, lane=tid&63, m=lane&15, q=lane>>4;
  int rowBase=blockIdx.x*64;
  // ---- stage W_agt into WA(=Tf region); input load covers latency ----
  stage_w(Wp_agt, WA, w, lane);
  bf16x8 af_a[4];
  load_af_f32(agts, af_a, rowBase + 16*w + m, M, q);
  f32x4 acc[8];
  __syncthreads();                       // W_agt landed
  mfma_lds(af_a, WA, acc, lane);
  __syncthreads();                       // all waves done reading WA before Tf overwrite
  // base = agts @ W_agt (C-frags) -> f32 LDS tile (band-local)
#pragma unroll
  for (int r=0;r<4;r++){
    int row=16*w+4*q+r;
#pragma unroll
    for (int t=0;t<8;t++) Tf[row*132 + t*16 + m] = acc[t][r];
  }
  // gather phase: 4 lanes per row, 32 channels each (band-local read of Tf)
  int grow=tid>>2, gch=tid&3;
  int a = rowBase + grow;
  float s[32];
#pragma unroll
  for (int c2=0;c2<8;c2++){
    float4 v = *(const float4*)(Tf + grow*132 + gch*32 + c2*4);
    s[c2*4]=v.x; s[c2*4+1]=v.y; s[c2*4+2]=v.z; s[c2*4+3]=v.w;
  }
  __syncthreads();                       // all waves done reading Tf
  stage_w(Wp_lin, WA, w, lane);          // issue W_lin; gather loop covers latency
  int cnt = 0;
  if (a < M){ cnt = counts[a]; cnt = cnt < CAP ? cnt : CAP; }
  for (int j=0;j<cnt;j++){
    int e = perm[(size_t)a*CAP + j];
    const __bf16* ep = edge_out + (size_t)e*DD + gch*32;
#pragma unroll
    for (int c2=0;c2<4;c2++){
      bf16x8 v = *(const bf16x8*)(ep + c2*8);
#pragma unroll
      for (int k=0;k<8;k++) s[c2*8+k] += (float)v[k];
    }
  }
  // GN + ReLU over the row (4-lane reduction)
  {
    float sm=0.f, sq=0.f;
#pragma unroll
    for (int k=0;k<32;k++){ sm+=s[k]; sq=fmaf(s[k],s[k],sq); }
    sm+=__shfl_xor(sm,1,64); sm+=__shfl_xor(sm,2,64);
    sq+=__shfl_xor(sq,1,64); sq+=__shfl_xor(sq,2,64);
    float mu=sm*(1.f/DD), rs=rsqrtf(sq*(1.f/DD)-mu*mu+EPS);
#pragma unroll
    for (int k=0;k<32;k++){
      int c=gch*32+k;
      s[k]=fmaxf((s[k]-mu)*rs*g_n[c]+b_n[c],0.f);
    }
  }
#pragma unroll
  for (int c2=0;c2<4;c2++)
    *(bf16x8*)(T + grow*136 + gch*32 + c2*8) = cvt8(s + c2*8);
  __syncthreads();                       // W_lin landed (T writes are band-local)
  // W_lin MFMA + GN + residual + ReLU
  bf16x8 af[4];
  read_af(T, af, w, lane);
  mfma_lds(af, WA, acc, lane);
  gn_frag<false>(acc, g_lin, b_lin, m);
#pragma unroll
  for (int r=0;r<4;r++){
    int row=rowBase+16*w+4*q+r;
    if (row<M){
#pragma unroll
      for (int t=0;t<8;t++){
        int col=t*16+m;
        float rr=agts[(size_t)row*DD+col];
        out[(size_t)row*DD+col]=fmaxf(acc[t][r]+rr,0.f);
      }
    }
  }
}

// ---------- path-B final (atomic fallback) ----------
__global__ __launch_bounds__(256)
void final_kernel(const float* __restrict__ accF, const float* __restrict__ g_n, const float* __restrict__ b_n,
                  const __bf16* __restrict__ Wp_lin, const float* __restrict__ g_lin, const float* __restrict__ b_lin,
                  const float* __restrict__ res, float* __restrict__ out, int M){
  __shared__ __bf16 Ab[64*136];
  __shared__ __bf16 WL[16384];
  int tid=threadIdx.x, w=tid>>6, lane=tid&63, m=lane&15, q=lane>>4;
  int rowBase=blockIdx.x*64;
  stage_w(Wp_lin, WL, w, lane);
  {
    int rl=tid>>2, qq=tid&3;
    int row=rowBase+rl;
    float v[32];
    float s=0.f, sq=0.f;
#pragma unroll
    for (int t8=0;t8<8;t8++){
      float4 x=make_float4(0.f,0.f,0.f,0.f);
      if (row<M) x=ld4(accF + (size_t)row*DD + qq*32 + t8*4);
      v[t8*4]=x.x; v[t8*4+1]=x.y; v[t8*4+2]=x.z; v[t8*4+3]=x.w;
      s  += x.x+x.y+x.z+x.w;
      sq += x.x*x.x+x.y*x.y+x.z*x.z+x.w*x.w;
    }
    s+=__shfl_xor(s,1,64); s+=__shfl_xor(s,2,64);
    sq+=__shfl_xor(sq,1,64); sq+=__shfl_xor(sq,2,64);
    float mu=s*(1.f/DD), rs=rsqrtf(sq*(1.f/DD)-mu*mu+EPS);
#pragma unroll
    for (int j=0;j<32;j++){
      int c=qq*32+j;
      v[j]=fmaxf((v[j]-mu)*rs*g_n[c]+b_n[c],0.f);
    }
#pragma unroll
    for (int s2=0;s2<4;s2++)
      *(bf16x8*)(Ab + rl*136 + qq*32 + s2*8) = cvt8(v+s2*8);
  }
  __syncthreads();
  bf16x8 af[4]; f32x4 acc[8];
  read_af(Ab, af, w, lane);
  mfma_lds(af, WL, acc, lane);
  gn_frag<false>(acc, g_lin, b_lin, m);
#pragma unroll
  for (int r=0;r<4;r++){
    int row=rowBase+16*w+4*q+r;
    if (row<M){
#pragma unroll
      for (int t=0;t<8;t++){
        int col=t*16+m;
        float rr=res[(size_t)row*DD+col];
        out[(size_t)row*DD+col]=fmaxf(acc[t][r]+rr,0.f);
      }
    }
  }
}

extern "C" void kernel_launch(void* const* d_in, const int* in_sizes, int n_in,
                              void* d_out, int out_size, void* d_ws, size_t ws_size,
                              hipStream_t stream){
  const float* agts     = (const float*)d_in[0];
  const float* ctx      = (const float*)d_in[1];
  const float* agt_ctrs = (const float*)d_in[2];
  const float* ctx_ctrs = (const float*)d_in[3];
  const float* W_dist1  = (const float*)d_in[4];
  const float* b_dist1  = (const float*)d_in[5];
  const float* W_dist2  = (const float*)d_in[6];
  const float* g_dist   = (const float*)d_in[7];
  const float* b_dist   = (const float*)d_in[8];
  const float* W_q      = (const float*)d_in[9];
  const float* g_q      = (const float*)d_in[10];
  const float* b_q      = (const float*)d_in[11];
  const float* W_c1     = (const float*)d_in[12];
  const float* g_c1     = (const float*)d_in[13];
  const float* b_c1     = (const float*)d_in[14];
  const float* W_c2     = (const float*)d_in[15];
  const float* W_agt    = (const float*)d_in[16];
  const float* g_n      = (const float*)d_in[17];
  const float* b_n      = (const float*)d_in[18];
  const float* W_lin    = (const float*)d_in[19];
  const float* g_lin    = (const float*)d_in[20];
  const float* b_lin    = (const float*)d_in[21];
  const int*   hi       = (const int*)d_in[22];
  const int*   wi       = (const int*)d_in[23];

  int nA = in_sizes[0]/DD, nC = in_sizes[1]/DD, nE = in_sizes[22];
  float* out = (float*)d_out;

  auto al = [](size_t x){ return (x + 255) & ~(size_t)255; };
  size_t oAq2 = 0;
  size_t oCc  = al(oAq2 + (size_t)nA*DD*2);
  size_t oWp  = al(oCc  + (size_t)nC*DD*2);
  size_t oCnt = al(oWp  + (size_t)8*16384*2);
  size_t oPerm= al(oCnt + (size_t)nA*4);
  size_t oTail= al(oPerm+ (size_t)nA*CAP*4);
  size_t needA = oTail + (size_t)nE*DD*2;   // edge_out
  bool bigA = (ws_size >= needA);

  char* ws = (char*)d_ws;
  __bf16* Aq2bf = (__bf16*)(ws + oAq2);
  __bf16* Ccbf  = (__bf16*)(ws + oCc);
  __bf16* Wp    = (__bf16*)(ws + oWp);
  int*    counts= (int*)   (ws + oCnt);
  int*    perm  = (int*)   (ws + oPerm);
  __bf16* edge_out = (__bf16*)(ws + oTail);
  float*  CF    = (float*)(ws + oCnt);      // path-B only (aliases counts/perm region)

  dim3 B(256);
  int gA=(nA+63)/64, gC=(nC+63)/64, gE=(nE+127)/128;
  int gBucket = bigA ? (nE+255)/256 : 0;

  // pack: 0=W_dist2 1=W_c1lo 2=W_c2 3=W_q 4=W_c1mid 5=W_c1hi 6=W_agt 7=W_lin
  pack_w<<<64,B,0,stream>>>(W_dist2, W_c1, W_c2, W_q,
                            W_c1+128*DD, W_c1+256*DD, W_agt, W_lin, Wp);
  if (bigA){
    hipMemsetAsync(counts, 0, (size_t)nA*4, stream);
    prep_kernel<<<gBucket+gA+gC,B,0,stream>>>(hi, nE, counts, perm,
        agts, Wp+3*16384, g_q, b_q, Wp+4*16384, Wp+6*16384, Aq2bf, nullptr, nA,
        ctx, Wp+5*16384, Ccbf, nC, gBucket, gA);
    edge_kernel<<<gE,B,0,stream>>>(agt_ctrs, ctx_ctrs, hi, wi,
        W_dist1, b_dist1, Wp+0, g_dist, b_dist,
        Wp+1*16384, g_c1, b_c1, Wp+2*16384,
        Aq2bf, Ccbf, nullptr, edge_out, nE);
    final_fused<<<gA,B,0,stream>>>(agts, Wp+6*16384, counts, perm, edge_out,
        g_n, b_n, Wp+7*16384, g_lin, b_lin, out, nA);
  } else {
    prep_kernel<<<gA+gC,B,0,stream>>>(hi, nE, counts, perm,
        agts, Wp+3*16384, g_q, b_q, Wp+4*16384, Wp+6*16384, Aq2bf, CF, nA,
        ctx, Wp+5*16384, Ccbf, nC, 0, gA);
    edge_kernel<<<gE,B,0,stream>>>(agt_ctrs, ctx_ctrs, hi, wi,
        W_dist1, b_dist1, Wp+0, g_dist, b_dist,
        Wp+1*16384, g_c1, b_c1, Wp+2*16384,
        Aq2bf, Ccbf, CF, nullptr, nE);
    final_kernel<<<gA,B,0,stream>>>(CF, g_n, b_n, Wp+7*16384, g_lin, b_lin, agts, out, nA);
  }
}

// Round 6
// 480.904 us; speedup vs baseline: 1.0627x; 1.0627x over previous
//
#include <hip/hip_runtime.h>
#include <math.h>

#define DD 128
#define CAP 32
constexpr float EPS = 1e-5f;

typedef __bf16 bf16x8 __attribute__((ext_vector_type(8)));
typedef float  f32x4  __attribute__((ext_vector_type(4)));

__device__ __forceinline__ float4 ld4(const float* p){ return *(const float4*)p; }

__device__ __forceinline__ bf16x8 cvt8(const float* p){
  bf16x8 r;
#pragma unroll
  for (int i=0;i<8;i++) r[i] = (__bf16)p[i];
  return r;
}

// ---------- weight pre-pack: B-frag-major bf16 ----------
__global__ __launch_bounds__(256)
void pack_w(const float* W0, const float* W1, const float* W2, const float* W3,
            const float* W4, const float* W5, const float* W6, const float* W7,
            __bf16* dst){
  int gidx = blockIdx.x*256 + threadIdx.x;
  int mat  = gidx >> 11;
  int i    = gidx & 2047;
  int lane = i & 63, frag = i >> 6;          // frag = tn*4+ks
  int tn = frag >> 2, ks = frag & 3;
  int n  = tn*16 + (lane & 15);
  int k0 = ks*32 + (lane >> 4)*8;
  const float* W;
  switch(mat){
    case 0: W=W0; break; case 1: W=W1; break; case 2: W=W2; break; case 3: W=W3; break;
    case 4: W=W4; break; case 5: W=W5; break; case 6: W=W6; break; default: W=W7; break;
  }
  __bf16* d = dst + (size_t)mat*16384 + (size_t)i*8;
#pragma unroll
  for (int j=0;j<8;j++) d[j] = (__bf16)W[(size_t)(k0+j)*DD + n];
}

// ---------- GroupNorm(1,128) in MFMA C-frag domain ----------
template<bool RELU>
__device__ __forceinline__ void gn_frag(f32x4 (&acc)[8], const float* __restrict__ g,
                                        const float* __restrict__ b, int m){
  float gv[8], bv[8];
#pragma unroll
  for (int t=0;t<8;t++){ gv[t]=g[t*16+m]; bv[t]=b[t*16+m]; }
#pragma unroll
  for (int r=0;r<4;r++){
    float s=0.f, sq=0.f;
#pragma unroll
    for (int t=0;t<8;t++){ float v=acc[t][r]; s+=v; sq=fmaf(v,v,sq); }
#pragma unroll
    for (int mk=1; mk<16; mk<<=1){ s+=__shfl_xor(s,mk,64); sq+=__shfl_xor(sq,mk,64); }
    float mu=s*(1.f/DD);
    float rs=rsqrtf(sq*(1.f/DD)-mu*mu+EPS);
#pragma unroll
    for (int t=0;t<8;t++){
      float v=(acc[t][r]-mu)*rs*gv[t]+bv[t];
      if (RELU) v=fmaxf(v,0.f);
      acc[t][r]=v;
    }
  }
}

// ---------- MFMA: acc = A_frags @ WL (LDS-staged weights) ----------
__device__ __forceinline__ void mfma_lds(const bf16x8 (&af)[4], const __bf16* WL,
                                         f32x4 (&acc)[8], int lane){
#pragma unroll
  for (int tn=0;tn<8;tn++){
    f32x4 a; a[0]=0.f; a[1]=0.f; a[2]=0.f; a[3]=0.f;
#pragma unroll
    for (int ks=0;ks<4;ks++){
      bf16x8 bf = *(const bf16x8*)(WL + ((tn*4+ks)*64 + lane)*8);
      a = __builtin_amdgcn_mfma_f32_16x16x32_bf16(af[ks], bf, a, 0,0,0);
    }
    acc[tn]=a;
  }
}

// ---------- async stage one packed 32KB weight matrix into LDS (4 waves) ----------
__device__ __forceinline__ void stage_w(const __bf16* __restrict__ Wg, __bf16* WL, int w, int lane){
#pragma unroll
  for (int j=0;j<8;j++){
    int off = ((w*8+j)<<10) + lane*16;   // bytes
    __builtin_amdgcn_global_load_lds(
      (const __attribute__((address_space(1))) void*)((const char*)Wg + off),
      (__attribute__((address_space(3))) void*)((char*)WL + ((w*8+j)<<10)),
      16, 0, 0);
  }
}

// ---------- async stage one packed 32KB weight matrix into LDS (8 waves) ----------
__device__ __forceinline__ void stage_w8(const __bf16* __restrict__ Wg, __bf16* WL, int w, int lane){
#pragma unroll
  for (int j=0;j<4;j++){
    int c = j*8 + w;
    int off = (c<<10) + lane*16;   // bytes
    __builtin_amdgcn_global_load_lds(
      (const __attribute__((address_space(1))) void*)((const char*)Wg + off),
      (__attribute__((address_space(3))) void*)((char*)WL + (c<<10)),
      16, 0, 0);
  }
}

__device__ __forceinline__ void read_af(const __bf16* T, bf16x8 (&af)[4], int w, int lane){
  int m=lane&15, q=lane>>4;
#pragma unroll
  for (int ks=0;ks<4;ks++)
    af[ks] = *(const bf16x8*)(T + (16*w+m)*136 + ks*32 + q*8);
}

__device__ __forceinline__ void write_cfrag_bf16(__bf16* T, const f32x4 (&acc)[8], int w, int lane){
  int m=lane&15, q=lane>>4;
#pragma unroll
  for (int r=0;r<4;r++){
    int row=16*w+4*q+r;
#pragma unroll
    for (int t=0;t<8;t++) T[row*136 + t*16 + m] = (__bf16)acc[t][r];
  }
}

__device__ __forceinline__ void load_af_f32(const float* X, bf16x8 (&af)[4], int row, int M, int q){
  if (row < M){
    const float* xr = X + (size_t)row*DD;
#pragma unroll
    for (int ks=0;ks<4;ks++){
      float t[8];
      *(float4*)t     = ld4(xr + ks*32 + q*8);
      *(float4*)(t+4) = ld4(xr + ks*32 + q*8 + 4);
      af[ks] = cvt8(t);
    }
  } else {
#pragma unroll
    for (int ks=0;ks<4;ks++){
#pragma unroll
      for (int j=0;j<8;j++) af[ks][j]=(__bf16)0.f;
    }
  }
}

// ---------- prep: [bucket build] + [Q->Aq2 (+base)] + [Cc], 128 rows / 8 waves ----------
__global__ __launch_bounds__(512)
void prep_kernel(const int* __restrict__ hi, int E, int* __restrict__ counts, int* __restrict__ perm,
                 const float* __restrict__ agts,
                 const __bf16* __restrict__ Wp_q, const float* __restrict__ g_q, const float* __restrict__ b_q,
                 const __bf16* __restrict__ Wp_mid, const __bf16* __restrict__ Wp_agt,
                 __bf16* __restrict__ Aq2bf, float* __restrict__ baseF, int nA,
                 const float* __restrict__ ctx, const __bf16* __restrict__ Wp_chi,
                 __bf16* __restrict__ Ccbf, int nC,
                 int gBucket, int gA){
  __shared__ __bf16 T[128*136];     // 34816 B
  __shared__ __bf16 WL[16384];      // 32768 B
  int b = blockIdx.x;
  if (b < gBucket){
    int e = b*512 + threadIdx.x;
    if (e < E){
      int a = hi[e];
      int slot = atomicAdd(&counts[a], 1);
      if (slot < CAP) perm[(size_t)a*CAP + slot] = e;
    }
    return;
  }
  b -= gBucket;
  int tid=threadIdx.x, w=tid>>6, lane=tid&63, m=lane&15, q=lane>>4;
  if (b < gA){
    stage_w8(Wp_q, WL, w, lane);             // issue W_q -> LDS
    int rowA = b*128 + 16*w + m;
    bf16x8 af_a[4];
    load_af_f32(agts, af_a, rowA, nA, q);    // covers staging latency
    f32x4 acc[8];
    __syncthreads();                         // WL(q) landed
    // Q = relu(gn(agts @ W_q)) -> LDS transpose (band-local)
    mfma_lds(af_a, WL, acc, lane);
    __syncthreads();                         // all waves done reading WL(q)
    stage_w8(Wp_mid, WL, w, lane);           // issue W_c1mid; hidden by gn+transpose
    gn_frag<true>(acc, g_q, b_q, m);
    write_cfrag_bf16(T, acc, w, lane);
    bf16x8 af_q[4];
    read_af(T, af_q, w, lane);
    __syncthreads();                         // WL(mid) landed
    // Aq2 = Q @ W_c1mid
    mfma_lds(af_q, WL, acc, lane);
#pragma unroll
    for (int r=0;r<4;r++){
      int row = b*128 + 16*w + 4*q + r;
      if (row < nA){
#pragma unroll
        for (int t=0;t<8;t++)
          Aq2bf[(size_t)row*DD + t*16 + m] = (__bf16)acc[t][r];
      }
    }
    if (baseF){
      __syncthreads();                       // all waves done reading WL(mid)
      stage_w8(Wp_agt, WL, w, lane);
      __syncthreads();                       // WL(agt) landed
      mfma_lds(af_a, WL, acc, lane);
#pragma unroll
      for (int r=0;r<4;r++){
        int row = b*128 + 16*w + 4*q + r;
        if (row < nA){
#pragma unroll
          for (int t=0;t<8;t++)
            baseF[(size_t)row*DD + t*16 + m] = acc[t][r];
        }
      }
    }
  } else {
    int bid = b - gA;
    stage_w8(Wp_chi, WL, w, lane);           // issue W_c1hi -> LDS
    int rowA = bid*128 + 16*w + m;
    bf16x8 af[4];
    load_af_f32(ctx, af, rowA, nC, q);       // covers staging latency
    f32x4 acc[8];
    __syncthreads();                         // WL(chi) landed
    mfma_lds(af, WL, acc, lane);
#pragma unroll
    for (int r=0;r<4;r++){
      int row = bid*128 + 16*w + 4*q + r;
      if (row < nC){
#pragma unroll
        for (int t=0;t<8;t++)
          Ccbf[(size_t)row*DD + t*16 + m] = (__bf16)acc[t][r];
      }
    }
  }
}

// ---------- fused edge kernel: 128 edges/block, 8 waves, LDS-staged weights ----------
__global__ __launch_bounds__(512)
void edge_kernel(const float* __restrict__ agt_ctrs, const float* __restrict__ ctx_ctrs,
                 const int* __restrict__ hi, const int* __restrict__ wi,
                 const float* __restrict__ W1, const float* __restrict__ B1,
                 const __bf16* __restrict__ Wp_d2, const float* __restrict__ g_dist, const float* __restrict__ b_dist,
                 const __bf16* __restrict__ Wp_c1, const float* __restrict__ g_c1, const float* __restrict__ b_c1,
                 const __bf16* __restrict__ Wp_c2,
                 const __bf16* __restrict__ Aq2, const __bf16* __restrict__ Cc,
                 float* __restrict__ accOut, __bf16* __restrict__ edge_out, int E){
  __shared__ __bf16 T[128*136];     // 34816 B
  __shared__ __bf16 WL[16384];      // 32768 B; one packed weight matrix, reloaded per stage
  int tid=threadIdx.x, w=tid>>6, lane=tid&63, m=lane&15, q=lane>>4;
  int eBase = blockIdx.x*128;
  // ---- gather prefetch (vector loads, issued first) ----
  int grow = tid>>2, gch = tid&3;   // grow 0..127, band-local to wave (tid>>6 == grow>>4)
  int ge = eBase + grow;
  int ghe=0, gwe=0;
  if (ge < E){ ghe = hi[ge]; gwe = wi[ge]; }
  bf16x8 ga[4], gc[4];
  {
    const __bf16* ap = Aq2 + (size_t)ghe*DD + gch*32;
    const __bf16* cp = Cc  + (size_t)gwe*DD + gch*32;
#pragma unroll
    for (int c2=0;c2<4;c2++){ ga[c2]=*(const bf16x8*)(ap+c2*8); gc[c2]=*(const bf16x8*)(cp+c2*8); }
  }
  // ---- issue W_dist2 -> LDS (covered by stage0 compute) ----
  stage_w8(Wp_d2, WL, w, lane);
  // ---- stage0: d1 = relu(delta @ W_dist1 + b1); 128 rows x 128 cols ----
  {
    int e0 = ((w>>2)<<6) + lane;    // row 0..127: waves 0-3 rows 0-63, waves 4-7 rows 64-127
    int wc = (w&3)*32;              // column band
    int e = eBase + e0;
    float dx=0.f, dy=0.f;
    if (e < E){
      int h0=hi[e], w0=wi[e];
      dx = agt_ctrs[2*h0]   - ctx_ctrs[2*w0];
      dy = agt_ctrs[2*h0+1] - ctx_ctrs[2*w0+1];
    }
#pragma unroll
    for (int s=0;s<4;s++){
      float t[8];
#pragma unroll
      for (int j=0;j<8;j++){
        int c = wc + s*8 + j;
        t[j] = fmaxf(fmaf(dx, W1[c], fmaf(dy, W1[DD+c], B1[c])), 0.f);
      }
      *(bf16x8*)(T + e0*136 + wc + s*8) = cvt8(t);
    }
  }
  __syncthreads();                       // T(stage0) ready + WL(d2) landed
  bf16x8 af[4]; f32x4 acc[8];
  // ---- stage1: d = relu(gn(d1 @ W_dist2)) ----
  read_af(T, af, w, lane);
  mfma_lds(af, WL, acc, lane);
  __syncthreads();                       // all waves done reading WL(d2)
  stage_w8(Wp_c1, WL, w, lane);          // issue W_c1lo; latency hidden by gn + transposes
  gn_frag<true>(acc, g_dist, b_dist, m);
  write_cfrag_bf16(T, acc, w, lane);
  // ---- stage2 prep: read d into regs, write Aq2[hi]+Cc[wi] sums into T ----
  read_af(T, af, w, lane);
#pragma unroll
  for (int c2=0;c2<4;c2++){
    float s[8];
#pragma unroll
    for (int j=0;j<8;j++) s[j] = (float)ga[c2][j] + (float)gc[c2][j];
    *(bf16x8*)(T + grow*136 + gch*32 + c2*8) = cvt8(s);
  }
  __syncthreads();                       // WL(c1) landed
  // ---- stage2: c = relu(gn(d @ W_c1lo + Aq2[hi] + Cc[wi])) ----
  mfma_lds(af, WL, acc, lane);
#pragma unroll
  for (int r=0;r<4;r++){
    int row = 16*w + 4*q + r;
#pragma unroll
    for (int t=0;t<8;t++)
      acc[t][r] += (float)T[row*136 + t*16 + m];
  }
  __syncthreads();                       // all waves done reading WL(c1)
  stage_w8(Wp_c2, WL, w, lane);          // issue W_c2; hidden by gn + transposes
  gn_frag<true>(acc, g_c1, b_c1, m);
  write_cfrag_bf16(T, acc, w, lane);
  read_af(T, af, w, lane);
  __syncthreads();                       // WL(c2) landed
  // ---- stage3: e_out = c @ W_c2 ----
  mfma_lds(af, WL, acc, lane);
  if (edge_out){
    // streaming bf16 store, row-major via band-local LDS transpose
    write_cfrag_bf16(T, acc, w, lane);
    if (ge < E){
      const __bf16* src = T + grow*136 + gch*32;
      __bf16* dst = edge_out + (size_t)ge*DD + gch*32;
#pragma unroll
      for (int c2=0;c2<4;c2++) *(bf16x8*)(dst + c2*8) = *(const bf16x8*)(src + c2*8);
    }
  } else {
#pragma unroll
    for (int r=0;r<4;r++){
      int row = 16*w + 4*q + r;
      if (eBase + row < E){
        int he = hi[eBase + row];
        float* dst = accOut + (size_t)he*DD + m;
#pragma unroll
        for (int t=0;t<8;t++)
          atomicAdd(dst + t*16, acc[t][r]);
      }
    }
  }
}

// ---------- path-A final: base MFMA + edge gather-sum + GN chain + residual ----------
// Weight staging aliased onto Tf (33792B >= 32768B) to keep LDS at 51200.
__global__ __launch_bounds__(256)
void final_fused(const float* __restrict__ agts, const __bf16* __restrict__ Wp_agt,
                 const int* __restrict__ counts, const int* __restrict__ perm,
                 const __bf16* __restrict__ edge_out,
                 const float* __restrict__ g_n, const float* __restrict__ b_n,
                 const __bf16* __restrict__ Wp_lin, const float* __restrict__ g_lin, const float* __restrict__ b_lin,
                 float* __restrict__ out, int M){
  __shared__ float Tf[64*132];           // 33792 B; doubles as weight-staging buffer
  __shared__ __bf16 T[64*136];
  __bf16* WA = (__bf16*)Tf;
  int tid=threadIdx.x, w=tid>>6, lane=tid&63, m=lane&15, q=lane>>4;
  int rowBase=blockIdx.x*64;
  // ---- stage W_agt into WA(=Tf region); input load covers latency ----
  stage_w(Wp_agt, WA, w, lane);
  bf16x8 af_a[4];
  load_af_f32(agts, af_a, rowBase + 16*w + m, M, q);
  f32x4 acc[8];
  __syncthreads();                       // W_agt landed
  mfma_lds(af_a, WA, acc, lane);
  __syncthreads();                       // all waves done reading WA before Tf overwrite
  // base = agts @ W_agt (C-frags) -> f32 LDS tile (band-local)
#pragma unroll
  for (int r=0;r<4;r++){
    int row=16*w+4*q+r;
#pragma unroll
    for (int t=0;t<8;t++) Tf[row*132 + t*16 + m] = acc[t][r];
  }
  // gather phase: 4 lanes per row, 32 channels each (band-local read of Tf)
  int grow=tid>>2, gch=tid&3;
  int a = rowBase + grow;
  float s[32];
#pragma unroll
  for (int c2=0;c2<8;c2++){
    float4 v = *(const float4*)(Tf + grow*132 + gch*32 + c2*4);
    s[c2*4]=v.x; s[c2*4+1]=v.y; s[c2*4+2]=v.z; s[c2*4+3]=v.w;
  }
  __syncthreads();                       // all waves done reading Tf
  stage_w(Wp_lin, WA, w, lane);          // issue W_lin; gather loop covers latency
  int cnt = 0;
  if (a < M){ cnt = counts[a]; cnt = cnt < CAP ? cnt : CAP; }
  for (int j=0;j<cnt;j++){
    int e = perm[(size_t)a*CAP + j];
    const __bf16* ep = edge_out + (size_t)e*DD + gch*32;
#pragma unroll
    for (int c2=0;c2<4;c2++){
      bf16x8 v = *(const bf16x8*)(ep + c2*8);
#pragma unroll
      for (int k=0;k<8;k++) s[c2*8+k] += (float)v[k];
    }
  }
  // GN + ReLU over the row (4-lane reduction)
  {
    float sm=0.f, sq=0.f;
#pragma unroll
    for (int k=0;k<32;k++){ sm+=s[k]; sq=fmaf(s[k],s[k],sq); }
    sm+=__shfl_xor(sm,1,64); sm+=__shfl_xor(sm,2,64);
    sq+=__shfl_xor(sq,1,64); sq+=__shfl_xor(sq,2,64);
    float mu=sm*(1.f/DD), rs=rsqrtf(sq*(1.f/DD)-mu*mu+EPS);
#pragma unroll
    for (int k=0;k<32;k++){
      int c=gch*32+k;
      s[k]=fmaxf((s[k]-mu)*rs*g_n[c]+b_n[c],0.f);
    }
  }
#pragma unroll
  for (int c2=0;c2<4;c2++)
    *(bf16x8*)(T + grow*136 + gch*32 + c2*8) = cvt8(s + c2*8);
  __syncthreads();                       // W_lin landed (T writes are band-local)
  // W_lin MFMA + GN + residual + ReLU
  bf16x8 af[4];
  read_af(T, af, w, lane);
  mfma_lds(af, WA, acc, lane);
  gn_frag<false>(acc, g_lin, b_lin, m);
#pragma unroll
  for (int r=0;r<4;r++){
    int row=rowBase+16*w+4*q+r;
    if (row<M){
#pragma unroll
      for (int t=0;t<8;t++){
        int col=t*16+m;
        float rr=agts[(size_t)row*DD+col];
        out[(size_t)row*DD+col]=fmaxf(acc[t][r]+rr,0.f);
      }
    }
  }
}

// ---------- path-B final (atomic fallback) ----------
__global__ __launch_bounds__(256)
void final_kernel(const float* __restrict__ accF, const float* __restrict__ g_n, const float* __restrict__ b_n,
                  const __bf16* __restrict__ Wp_lin, const float* __restrict__ g_lin, const float* __restrict__ b_lin,
                  const float* __restrict__ res, float* __restrict__ out, int M){
  __shared__ __bf16 Ab[64*136];
  __shared__ __bf16 WL[16384];
  int tid=threadIdx.x, w=tid>>6, lane=tid&63, m=lane&15, q=lane>>4;
  int rowBase=blockIdx.x*64;
  stage_w(Wp_lin, WL, w, lane);
  {
    int rl=tid>>2, qq=tid&3;
    int row=rowBase+rl;
    float v[32];
    float s=0.f, sq=0.f;
#pragma unroll
    for (int t8=0;t8<8;t8++){
      float4 x=make_float4(0.f,0.f,0.f,0.f);
      if (row<M) x=ld4(accF + (size_t)row*DD + qq*32 + t8*4);
      v[t8*4]=x.x; v[t8*4+1]=x.y; v[t8*4+2]=x.z; v[t8*4+3]=x.w;
      s  += x.x+x.y+x.z+x.w;
      sq += x.x*x.x+x.y*x.y+x.z*x.z+x.w*x.w;
    }
    s+=__shfl_xor(s,1,64); s+=__shfl_xor(s,2,64);
    sq+=__shfl_xor(sq,1,64); sq+=__shfl_xor(sq,2,64);
    float mu=s*(1.f/DD), rs=rsqrtf(sq*(1.f/DD)-mu*mu+EPS);
#pragma unroll
    for (int j=0;j<32;j++){
      int c=qq*32+j;
      v[j]=fmaxf((v[j]-mu)*rs*g_n[c]+b_n[c],0.f);
    }
#pragma unroll
    for (int s2=0;s2<4;s2++)
      *(bf16x8*)(Ab + rl*136 + qq*32 + s2*8) = cvt8(v+s2*8);
  }
  __syncthreads();
  bf16x8 af[4]; f32x4 acc[8];
  read_af(Ab, af, w, lane);
  mfma_lds(af, WL, acc, lane);
  gn_frag<false>(acc, g_lin, b_lin, m);
#pragma unroll
  for (int r=0;r<4;r++){
    int row=rowBase+16*w+4*q+r;
    if (row<M){
#pragma unroll
      for (int t=0;t<8;t++){
        int col=t*16+m;
        float rr=res[(size_t)row*DD+col];
        out[(size_t)row*DD+col]=fmaxf(acc[t][r]+rr,0.f);
      }
    }
  }
}

extern "C" void kernel_launch(void* const* d_in, const int* in_sizes, int n_in,
                              void* d_out, int out_size, void* d_ws, size_t ws_size,
                              hipStream_t stream){
  const float* agts     = (const float*)d_in[0];
  const float* ctx      = (const float*)d_in[1];
  const float* agt_ctrs = (const float*)d_in[2];
  const float* ctx_ctrs = (const float*)d_in[3];
  const float* W_dist1  = (const float*)d_in[4];
  const float* b_dist1  = (const float*)d_in[5];
  const float* W_dist2  = (const float*)d_in[6];
  const float* g_dist   = (const float*)d_in[7];
  const float* b_dist   = (const float*)d_in[8];
  const float* W_q      = (const float*)d_in[9];
  const float* g_q      = (const float*)d_in[10];
  const float* b_q      = (const float*)d_in[11];
  const float* W_c1     = (const float*)d_in[12];
  const float* g_c1     = (const float*)d_in[13];
  const float* b_c1     = (const float*)d_in[14];
  const float* W_c2     = (const float*)d_in[15];
  const float* W_agt    = (const float*)d_in[16];
  const float* g_n      = (const float*)d_in[17];
  const float* b_n      = (const float*)d_in[18];
  const float* W_lin    = (const float*)d_in[19];
  const float* g_lin    = (const float*)d_in[20];
  const float* b_lin    = (const float*)d_in[21];
  const int*   hi       = (const int*)d_in[22];
  const int*   wi       = (const int*)d_in[23];

  int nA = in_sizes[0]/DD, nC = in_sizes[1]/DD, nE = in_sizes[22];
  float* out = (float*)d_out;

  auto al = [](size_t x){ return (x + 255) & ~(size_t)255; };
  size_t oAq2 = 0;
  size_t oCc  = al(oAq2 + (size_t)nA*DD*2);
  size_t oWp  = al(oCc  + (size_t)nC*DD*2);
  size_t oCnt = al(oWp  + (size_t)8*16384*2);
  size_t oPerm= al(oCnt + (size_t)nA*4);
  size_t oTail= al(oPerm+ (size_t)nA*CAP*4);
  size_t needA = oTail + (size_t)nE*DD*2;   // edge_out
  bool bigA = (ws_size >= needA);

  char* ws = (char*)d_ws;
  __bf16* Aq2bf = (__bf16*)(ws + oAq2);
  __bf16* Ccbf  = (__bf16*)(ws + oCc);
  __bf16* Wp    = (__bf16*)(ws + oWp);
  int*    counts= (int*)   (ws + oCnt);
  int*    perm  = (int*)   (ws + oPerm);
  __bf16* edge_out = (__bf16*)(ws + oTail);
  float*  CF    = (float*)(ws + oCnt);      // path-B only (aliases counts/perm region)

  dim3 B(256), B2(512);
  int gA2=(nA+127)/128, gC2=(nC+127)/128, gA=(nA+63)/64, gE=(nE+127)/128;
  int gBucket = bigA ? (nE+511)/512 : 0;

  // pack: 0=W_dist2 1=W_c1lo 2=W_c2 3=W_q 4=W_c1mid 5=W_c1hi 6=W_agt 7=W_lin
  pack_w<<<64,B,0,stream>>>(W_dist2, W_c1, W_c2, W_q,
                            W_c1+128*DD, W_c1+256*DD, W_agt, W_lin, Wp);
  if (bigA){
    hipMemsetAsync(counts, 0, (size_t)nA*4, stream);
    prep_kernel<<<gBucket+gA2+gC2,B2,0,stream>>>(hi, nE, counts, perm,
        agts, Wp+3*16384, g_q, b_q, Wp+4*16384, Wp+6*16384, Aq2bf, nullptr, nA,
        ctx, Wp+5*16384, Ccbf, nC, gBucket, gA2);
    edge_kernel<<<gE,B2,0,stream>>>(agt_ctrs, ctx_ctrs, hi, wi,
        W_dist1, b_dist1, Wp+0, g_dist, b_dist,
        Wp+1*16384, g_c1, b_c1, Wp+2*16384,
        Aq2bf, Ccbf, nullptr, edge_out, nE);
    final_fused<<<gA,B,0,stream>>>(agts, Wp+6*16384, counts, perm, edge_out,
        g_n, b_n, Wp+7*16384, g_lin, b_lin, out, nA);
  } else {
    prep_kernel<<<gA2+gC2,B2,0,stream>>>(hi, nE, counts, perm,
        agts, Wp+3*16384, g_q, b_q, Wp+4*16384, Wp+6*16384, Aq2bf, CF, nA,
        ctx, Wp+5*16384, Ccbf, nC, 0, gA2);
    edge_kernel<<<gE,B2,0,stream>>>(agt_ctrs, ctx_ctrs, hi, wi,
        W_dist1, b_dist1, Wp+0, g_dist, b_dist,
        Wp+1*16384, g_c1, b_c1, Wp+2*16384,
        Aq2bf, Ccbf, CF, nullptr, nE);
    final_kernel<<<gA,B,0,stream>>>(CF, g_n, b_n, Wp+7*16384, g_lin, b_lin, agts, out, nA);
  }
}

// Round 7
// 462.642 us; speedup vs baseline: 1.1046x; 1.0395x over previous
//
#include <hip/hip_runtime.h>
#include <math.h>

#define DD 128
#define CAP 32
constexpr float EPS = 1e-5f;

typedef __bf16 bf16x8 __attribute__((ext_vector_type(8)));
typedef float  f32x4  __attribute__((ext_vector_type(4)));

__device__ __forceinline__ float4 ld4(const float* p){ return *(const float4*)p; }

__device__ __forceinline__ bf16x8 cvt8(const float* p){
  bf16x8 r;
#pragma unroll
  for (int i=0;i<8;i++) r[i] = (__bf16)p[i];
  return r;
}

// ---------- weight pre-pack: B-frag-major bf16 ----------
__global__ __launch_bounds__(256)
void pack_w(const float* W0, const float* W1, const float* W2, const float* W3,
            const float* W4, const float* W5, const float* W6, const float* W7,
            __bf16* dst){
  int gidx = blockIdx.x*256 + threadIdx.x;
  int mat  = gidx >> 11;
  int i    = gidx & 2047;
  int lane = i & 63, frag = i >> 6;          // frag = tn*4+ks
  int tn = frag >> 2, ks = frag & 3;
  int n  = tn*16 + (lane & 15);
  int k0 = ks*32 + (lane >> 4)*8;
  const float* W;
  switch(mat){
    case 0: W=W0; break; case 1: W=W1; break; case 2: W=W2; break; case 3: W=W3; break;
    case 4: W=W4; break; case 5: W=W5; break; case 6: W=W6; break; default: W=W7; break;
  }
  __bf16* d = dst + (size_t)mat*16384 + (size_t)i*8;
#pragma unroll
  for (int j=0;j<8;j++) d[j] = (__bf16)W[(size_t)(k0+j)*DD + n];
}

// ---------- GroupNorm(1,128) in MFMA C-frag domain ----------
template<bool RELU>
__device__ __forceinline__ void gn_frag(f32x4 (&acc)[8], const float* __restrict__ g,
                                        const float* __restrict__ b, int m){
  float gv[8], bv[8];
#pragma unroll
  for (int t=0;t<8;t++){ gv[t]=g[t*16+m]; bv[t]=b[t*16+m]; }
#pragma unroll
  for (int r=0;r<4;r++){
    float s=0.f, sq=0.f;
#pragma unroll
    for (int t=0;t<8;t++){ float v=acc[t][r]; s+=v; sq=fmaf(v,v,sq); }
#pragma unroll
    for (int mk=1; mk<16; mk<<=1){ s+=__shfl_xor(s,mk,64); sq+=__shfl_xor(sq,mk,64); }
    float mu=s*(1.f/DD);
    float rs=rsqrtf(sq*(1.f/DD)-mu*mu+EPS);
#pragma unroll
    for (int t=0;t<8;t++){
      float v=(acc[t][r]-mu)*rs*gv[t]+bv[t];
      if (RELU) v=fmaxf(v,0.f);
      acc[t][r]=v;
    }
  }
}

// ---------- MFMA: acc = A_frags @ WL (LDS-staged weights) ----------
__device__ __forceinline__ void mfma_lds(const bf16x8 (&af)[4], const __bf16* WL,
                                         f32x4 (&acc)[8], int lane){
#pragma unroll
  for (int tn=0;tn<8;tn++){
    f32x4 a; a[0]=0.f; a[1]=0.f; a[2]=0.f; a[3]=0.f;
#pragma unroll
    for (int ks=0;ks<4;ks++){
      bf16x8 bf = *(const bf16x8*)(WL + ((tn*4+ks)*64 + lane)*8);
      a = __builtin_amdgcn_mfma_f32_16x16x32_bf16(af[ks], bf, a, 0,0,0);
    }
    acc[tn]=a;
  }
}

// ---------- async stage one packed 32KB weight matrix into LDS (4 waves) ----------
__device__ __forceinline__ void stage_w(const __bf16* __restrict__ Wg, __bf16* WL, int w, int lane){
#pragma unroll
  for (int j=0;j<8;j++){
    int off = ((w*8+j)<<10) + lane*16;   // bytes
    __builtin_amdgcn_global_load_lds(
      (const __attribute__((address_space(1))) void*)((const char*)Wg + off),
      (__attribute__((address_space(3))) void*)((char*)WL + ((w*8+j)<<10)),
      16, 0, 0);
  }
}

// ---------- async stage one packed 32KB weight matrix into LDS (8 waves) ----------
__device__ __forceinline__ void stage_w8(const __bf16* __restrict__ Wg, __bf16* WL, int w, int lane){
#pragma unroll
  for (int j=0;j<4;j++){
    int c = j*8 + w;
    int off = (c<<10) + lane*16;   // bytes
    __builtin_amdgcn_global_load_lds(
      (const __attribute__((address_space(1))) void*)((const char*)Wg + off),
      (__attribute__((address_space(3))) void*)((char*)WL + (c<<10)),
      16, 0, 0);
  }
}

__device__ __forceinline__ void read_af(const __bf16* T, bf16x8 (&af)[4], int w, int lane){
  int m=lane&15, q=lane>>4;
#pragma unroll
  for (int ks=0;ks<4;ks++)
    af[ks] = *(const bf16x8*)(T + (16*w+m)*136 + ks*32 + q*8);
}

__device__ __forceinline__ void write_cfrag_bf16(__bf16* T, const f32x4 (&acc)[8], int w, int lane){
  int m=lane&15, q=lane>>4;
#pragma unroll
  for (int r=0;r<4;r++){
    int row=16*w+4*q+r;
#pragma unroll
    for (int t=0;t<8;t++) T[row*136 + t*16 + m] = (__bf16)acc[t][r];
  }
}

__device__ __forceinline__ void load_af_f32(const float* X, bf16x8 (&af)[4], int row, int M, int q){
  if (row < M){
    const float* xr = X + (size_t)row*DD;
#pragma unroll
    for (int ks=0;ks<4;ks++){
      float t[8];
      *(float4*)t     = ld4(xr + ks*32 + q*8);
      *(float4*)(t+4) = ld4(xr + ks*32 + q*8 + 4);
      af[ks] = cvt8(t);
    }
  } else {
#pragma unroll
    for (int ks=0;ks<4;ks++){
#pragma unroll
      for (int j=0;j<8;j++) af[ks][j]=(__bf16)0.f;
    }
  }
}

// ---------- prep: [bucket build] + [Q->Aq2 (+base)] + [Cc], 128 rows / 8 waves ----------
__global__ __launch_bounds__(512)
void prep_kernel(const int* __restrict__ hi, int E, int* __restrict__ counts, int* __restrict__ perm,
                 const float* __restrict__ agts,
                 const __bf16* __restrict__ Wp_q, const float* __restrict__ g_q, const float* __restrict__ b_q,
                 const __bf16* __restrict__ Wp_mid, const __bf16* __restrict__ Wp_agt,
                 __bf16* __restrict__ Aq2bf, float* __restrict__ baseF, int nA,
                 const float* __restrict__ ctx, const __bf16* __restrict__ Wp_chi,
                 __bf16* __restrict__ Ccbf, int nC,
                 int gBucket, int gA){
  __shared__ __bf16 T[128*136];     // 34816 B
  __shared__ __bf16 WL[16384];      // 32768 B
  int b = blockIdx.x;
  if (b < gBucket){
    int e = b*512 + threadIdx.x;
    if (e < E){
      int a = hi[e];
      int slot = atomicAdd(&counts[a], 1);
      if (slot < CAP) perm[(size_t)a*CAP + slot] = e;
    }
    return;
  }
  b -= gBucket;
  int tid=threadIdx.x, w=tid>>6, lane=tid&63, m=lane&15, q=lane>>4;
  if (b < gA){
    stage_w8(Wp_q, WL, w, lane);             // issue W_q -> LDS
    int rowA = b*128 + 16*w + m;
    bf16x8 af_a[4];
    load_af_f32(agts, af_a, rowA, nA, q);    // covers staging latency
    f32x4 acc[8];
    __syncthreads();                         // WL(q) landed
    // Q = relu(gn(agts @ W_q)) -> LDS transpose (band-local)
    mfma_lds(af_a, WL, acc, lane);
    __syncthreads();                         // all waves done reading WL(q)
    stage_w8(Wp_mid, WL, w, lane);           // issue W_c1mid; hidden by gn+transpose
    gn_frag<true>(acc, g_q, b_q, m);
    write_cfrag_bf16(T, acc, w, lane);
    bf16x8 af_q[4];
    read_af(T, af_q, w, lane);
    __syncthreads();                         // WL(mid) landed
    // Aq2 = Q @ W_c1mid
    mfma_lds(af_q, WL, acc, lane);
#pragma unroll
    for (int r=0;r<4;r++){
      int row = b*128 + 16*w + 4*q + r;
      if (row < nA){
#pragma unroll
        for (int t=0;t<8;t++)
          Aq2bf[(size_t)row*DD + t*16 + m] = (__bf16)acc[t][r];
      }
    }
    if (baseF){
      __syncthreads();                       // all waves done reading WL(mid)
      stage_w8(Wp_agt, WL, w, lane);
      __syncthreads();                       // WL(agt) landed
      mfma_lds(af_a, WL, acc, lane);
#pragma unroll
      for (int r=0;r<4;r++){
        int row = b*128 + 16*w + 4*q + r;
        if (row < nA){
#pragma unroll
          for (int t=0;t<8;t++)
            baseF[(size_t)row*DD + t*16 + m] = acc[t][r];
        }
      }
    }
  } else {
    int bid = b - gA;
    stage_w8(Wp_chi, WL, w, lane);           // issue W_c1hi -> LDS
    int rowA = bid*128 + 16*w + m;
    bf16x8 af[4];
    load_af_f32(ctx, af, rowA, nC, q);       // covers staging latency
    f32x4 acc[8];
    __syncthreads();                         // WL(chi) landed
    mfma_lds(af, WL, acc, lane);
#pragma unroll
    for (int r=0;r<4;r++){
      int row = bid*128 + 16*w + 4*q + r;
      if (row < nC){
#pragma unroll
        for (int t=0;t<8;t++)
          Ccbf[(size_t)row*DD + t*16 + m] = (__bf16)acc[t][r];
      }
    }
  }
}

// ---------- fused edge kernel: 128 edges/block, 8 waves, LDS-staged weights ----------
__global__ __launch_bounds__(512)
void edge_kernel(const float* __restrict__ agt_ctrs, const float* __restrict__ ctx_ctrs,
                 const int* __restrict__ hi, const int* __restrict__ wi,
                 const float* __restrict__ W1, const float* __restrict__ B1,
                 const __bf16* __restrict__ Wp_d2, const float* __restrict__ g_dist, const float* __restrict__ b_dist,
                 const __bf16* __restrict__ Wp_c1, const float* __restrict__ g_c1, const float* __restrict__ b_c1,
                 const __bf16* __restrict__ Wp_c2,
                 const __bf16* __restrict__ Aq2, const __bf16* __restrict__ Cc,
                 float* __restrict__ accOut, __bf16* __restrict__ edge_out, int E){
  __shared__ __bf16 T[128*136];     // 34816 B
  __shared__ __bf16 WL[16384];      // 32768 B; one packed weight matrix, reloaded per stage
  int tid=threadIdx.x, w=tid>>6, lane=tid&63, m=lane&15, q=lane>>4;
  int eBase = blockIdx.x*128;
  // ---- gather prefetch (vector loads, issued first) ----
  int grow = tid>>2, gch = tid&3;   // grow 0..127, band-local to wave (tid>>6 == grow>>4)
  int ge = eBase + grow;
  int ghe=0, gwe=0;
  if (ge < E){ ghe = hi[ge]; gwe = wi[ge]; }
  bf16x8 ga[4], gc[4];
  {
    const __bf16* ap = Aq2 + (size_t)ghe*DD + gch*32;
    const __bf16* cp = Cc  + (size_t)gwe*DD + gch*32;
#pragma unroll
    for (int c2=0;c2<4;c2++){ ga[c2]=*(const bf16x8*)(ap+c2*8); gc[c2]=*(const bf16x8*)(cp+c2*8); }
  }
  // ---- issue W_dist2 -> LDS (covered by stage0 compute) ----
  stage_w8(Wp_d2, WL, w, lane);
  // ---- stage0: d1 = relu(delta @ W_dist1 + b1); 128 rows x 128 cols ----
  {
    int e0 = ((w>>2)<<6) + lane;    // row 0..127: waves 0-3 rows 0-63, waves 4-7 rows 64-127
    int wc = (w&3)*32;              // column band
    int e = eBase + e0;
    float dx=0.f, dy=0.f;
    if (e < E){
      int h0=hi[e], w0=wi[e];
      dx = agt_ctrs[2*h0]   - ctx_ctrs[2*w0];
      dy = agt_ctrs[2*h0+1] - ctx_ctrs[2*w0+1];
    }
#pragma unroll
    for (int s=0;s<4;s++){
      float t[8];
#pragma unroll
      for (int j=0;j<8;j++){
        int c = wc + s*8 + j;
        t[j] = fmaxf(fmaf(dx, W1[c], fmaf(dy, W1[DD+c], B1[c])), 0.f);
      }
      *(bf16x8*)(T + e0*136 + wc + s*8) = cvt8(t);
    }
  }
  __syncthreads();                       // T(stage0) ready + WL(d2) landed
  bf16x8 af[4]; f32x4 acc[8];
  // ---- stage1: d = relu(gn(d1 @ W_dist2)) ----
  read_af(T, af, w, lane);
  mfma_lds(af, WL, acc, lane);
  __syncthreads();                       // all waves done reading WL(d2)
  stage_w8(Wp_c1, WL, w, lane);          // issue W_c1lo; latency hidden by gn + transposes
  gn_frag<true>(acc, g_dist, b_dist, m);
  write_cfrag_bf16(T, acc, w, lane);
  // ---- stage2 prep: read d into regs, write Aq2[hi]+Cc[wi] sums into T ----
  read_af(T, af, w, lane);
#pragma unroll
  for (int c2=0;c2<4;c2++){
    float s[8];
#pragma unroll
    for (int j=0;j<8;j++) s[j] = (float)ga[c2][j] + (float)gc[c2][j];
    *(bf16x8*)(T + grow*136 + gch*32 + c2*8) = cvt8(s);
  }
  __syncthreads();                       // WL(c1) landed
  // ---- stage2: c = relu(gn(d @ W_c1lo + Aq2[hi] + Cc[wi])) ----
  mfma_lds(af, WL, acc, lane);
#pragma unroll
  for (int r=0;r<4;r++){
    int row = 16*w + 4*q + r;
#pragma unroll
    for (int t=0;t<8;t++)
      acc[t][r] += (float)T[row*136 + t*16 + m];
  }
  __syncthreads();                       // all waves done reading WL(c1)
  stage_w8(Wp_c2, WL, w, lane);          // issue W_c2; hidden by gn + transposes
  gn_frag<true>(acc, g_c1, b_c1, m);
  write_cfrag_bf16(T, acc, w, lane);
  read_af(T, af, w, lane);
  __syncthreads();                       // WL(c2) landed
  // ---- stage3: e_out = c @ W_c2 ----
  mfma_lds(af, WL, acc, lane);
  if (edge_out){
    // streaming bf16 store, row-major via band-local LDS transpose
    write_cfrag_bf16(T, acc, w, lane);
    if (ge < E){
      const __bf16* src = T + grow*136 + gch*32;
      __bf16* dst = edge_out + (size_t)ge*DD + gch*32;
#pragma unroll
      for (int c2=0;c2<4;c2++) *(bf16x8*)(dst + c2*8) = *(const bf16x8*)(src + c2*8);
    }
  } else {
#pragma unroll
    for (int r=0;r<4;r++){
      int row = 16*w + 4*q + r;
      if (eBase + row < E){
        int he = hi[eBase + row];
        float* dst = accOut + (size_t)he*DD + m;
#pragma unroll
        for (int t=0;t<8;t++)
          atomicAdd(dst + t*16, acc[t][r]);
      }
    }
  }
}

// ---------- path-A final: base MFMA + edge gather-sum + GN chain + residual ----------
// Gather loop is 2-deep software-pipelined; counts/first-edge prefetch hoisted to entry
// so its latency hides under W_agt staging + base MFMA.
__global__ __launch_bounds__(256)
void final_fused(const float* __restrict__ agts, const __bf16* __restrict__ Wp_agt,
                 const int* __restrict__ counts, const int* __restrict__ perm,
                 const __bf16* __restrict__ edge_out,
                 const float* __restrict__ g_n, const float* __restrict__ b_n,
                 const __bf16* __restrict__ Wp_lin, const float* __restrict__ g_lin, const float* __restrict__ b_lin,
                 float* __restrict__ out, int M){
  __shared__ float Tf[64*132];           // 33792 B; doubles as weight-staging buffer
  __shared__ __bf16 T[64*136];
  __bf16* WA = (__bf16*)Tf;
  int tid=threadIdx.x, w=tid>>6, lane=tid&63, m=lane&15, q=lane>>4;
  int rowBase=blockIdx.x*64;
  // ---- gather chain head: issue counts + first edge row at kernel entry ----
  int grow=tid>>2, gch=tid&3;
  int a = rowBase + grow;
  int cnt = 0;
  if (a < M){ cnt = counts[a]; cnt = cnt < CAP ? cnt : CAP; }
  const int* pp = perm + (size_t)a*CAP;
  bf16x8 c0,c1,c2,c3;
#pragma unroll
  for (int k=0;k<8;k++){ c0[k]=(__bf16)0.f; c1[k]=(__bf16)0.f; c2[k]=(__bf16)0.f; c3[k]=(__bf16)0.f; }
  if (cnt > 0){
    const __bf16* ep = edge_out + (size_t)pp[0]*DD + gch*32;
    c0=*(const bf16x8*)(ep);    c1=*(const bf16x8*)(ep+8);
    c2=*(const bf16x8*)(ep+16); c3=*(const bf16x8*)(ep+24);
  }
  // ---- stage W_agt into WA(=Tf region); input load covers latency ----
  stage_w(Wp_agt, WA, w, lane);
  bf16x8 af_a[4];
  load_af_f32(agts, af_a, rowBase + 16*w + m, M, q);
  f32x4 acc[8];
  __syncthreads();                       // W_agt landed
  mfma_lds(af_a, WA, acc, lane);
  __syncthreads();                       // all waves done reading WA before Tf overwrite
  // base = agts @ W_agt (C-frags) -> f32 LDS tile (band-local)
#pragma unroll
  for (int r=0;r<4;r++){
    int row=16*w+4*q+r;
#pragma unroll
    for (int t=0;t<8;t++) Tf[row*132 + t*16 + m] = acc[t][r];
  }
  // gather phase: 4 lanes per row, 32 channels each (band-local read of Tf)
  float s[32];
#pragma unroll
  for (int c2i=0;c2i<8;c2i++){
    float4 v = *(const float4*)(Tf + grow*132 + gch*32 + c2i*4);
    s[c2i*4]=v.x; s[c2i*4+1]=v.y; s[c2i*4+2]=v.z; s[c2i*4+3]=v.w;
  }
  __syncthreads();                       // all waves done reading Tf
  stage_w(Wp_lin, WA, w, lane);          // issue W_lin; gather loop covers latency
  // ---- 2-deep pipelined edge gather: issue j+1 loads before consuming j ----
  for (int j=1; j<cnt; j++){
    const __bf16* en = edge_out + (size_t)pp[j]*DD + gch*32;
    bf16x8 n0=*(const bf16x8*)(en),    n1=*(const bf16x8*)(en+8),
           n2=*(const bf16x8*)(en+16), n3=*(const bf16x8*)(en+24);
#pragma unroll
    for (int k=0;k<8;k++){
      s[k]    += (float)c0[k];
      s[8+k]  += (float)c1[k];
      s[16+k] += (float)c2[k];
      s[24+k] += (float)c3[k];
    }
    c0=n0; c1=n1; c2=n2; c3=n3;
  }
  if (cnt > 0){
#pragma unroll
    for (int k=0;k<8;k++){
      s[k]    += (float)c0[k];
      s[8+k]  += (float)c1[k];
      s[16+k] += (float)c2[k];
      s[24+k] += (float)c3[k];
    }
  }
  // GN + ReLU over the row (4-lane reduction)
  {
    float sm=0.f, sq=0.f;
#pragma unroll
    for (int k=0;k<32;k++){ sm+=s[k]; sq=fmaf(s[k],s[k],sq); }
    sm+=__shfl_xor(sm,1,64); sm+=__shfl_xor(sm,2,64);
    sq+=__shfl_xor(sq,1,64); sq+=__shfl_xor(sq,2,64);
    float mu=sm*(1.f/DD), rs=rsqrtf(sq*(1.f/DD)-mu*mu+EPS);
#pragma unroll
    for (int k=0;k<32;k++){
      int c=gch*32+k;
      s[k]=fmaxf((s[k]-mu)*rs*g_n[c]+b_n[c],0.f);
    }
  }
#pragma unroll
  for (int c2i=0;c2i<4;c2i++)
    *(bf16x8*)(T + grow*136 + gch*32 + c2i*8) = cvt8(s + c2i*8);
  __syncthreads();                       // W_lin landed (T writes are band-local)
  // W_lin MFMA + GN + residual + ReLU
  bf16x8 af[4];
  read_af(T, af, w, lane);
  mfma_lds(af, WA, acc, lane);
  gn_frag<false>(acc, g_lin, b_lin, m);
#pragma unroll
  for (int r=0;r<4;r++){
    int row=rowBase+16*w+4*q+r;
    if (row<M){
#pragma unroll
      for (int t=0;t<8;t++){
        int col=t*16+m;
        float rr=agts[(size_t)row*DD+col];
        out[(size_t)row*DD+col]=fmaxf(acc[t][r]+rr,0.f);
      }
    }
  }
}

// ---------- path-B final (atomic fallback) ----------
__global__ __launch_bounds__(256)
void final_kernel(const float* __restrict__ accF, const float* __restrict__ g_n, const float* __restrict__ b_n,
                  const __bf16* __restrict__ Wp_lin, const float* __restrict__ g_lin, const float* __restrict__ b_lin,
                  const float* __restrict__ res, float* __restrict__ out, int M){
  __shared__ __bf16 Ab[64*136];
  __shared__ __bf16 WL[16384];
  int tid=threadIdx.x, w=tid>>6, lane=tid&63, m=lane&15, q=lane>>4;
  int rowBase=blockIdx.x*64;
  stage_w(Wp_lin, WL, w, lane);
  {
    int rl=tid>>2, qq=tid&3;
    int row=rowBase+rl;
    float v[32];
    float s=0.f, sq=0.f;
#pragma unroll
    for (int t8=0;t8<8;t8++){
      float4 x=make_float4(0.f,0.f,0.f,0.f);
      if (row<M) x=ld4(accF + (size_t)row*DD + qq*32 + t8*4);
      v[t8*4]=x.x; v[t8*4+1]=x.y; v[t8*4+2]=x.z; v[t8*4+3]=x.w;
      s  += x.x+x.y+x.z+x.w;
      sq += x.x*x.x+x.y*x.y+x.z*x.z+x.w*x.w;
    }
    s+=__shfl_xor(s,1,64); s+=__shfl_xor(s,2,64);
    sq+=__shfl_xor(sq,1,64); sq+=__shfl_xor(sq,2,64);
    float mu=s*(1.f/DD), rs=rsqrtf(sq*(1.f/DD)-mu*mu+EPS);
#pragma unroll
    for (int j=0;j<32;j++){
      int c=qq*32+j;
      v[j]=fmaxf((v[j]-mu)*rs*g_n[c]+b_n[c],0.f);
    }
#pragma unroll
    for (int s2=0;s2<4;s2++)
      *(bf16x8*)(Ab + rl*136 + qq*32 + s2*8) = cvt8(v+s2*8);
  }
  __syncthreads();
  bf16x8 af[4]; f32x4 acc[8];
  read_af(Ab, af, w, lane);
  mfma_lds(af, WL, acc, lane);
  gn_frag<false>(acc, g_lin, b_lin, m);
#pragma unroll
  for (int r=0;r<4;r++){
    int row=rowBase+16*w+4*q+r;
    if (row<M){
#pragma unroll
      for (int t=0;t<8;t++){
        int col=t*16+m;
        float rr=res[(size_t)row*DD+col];
        out[(size_t)row*DD+col]=fmaxf(acc[t][r]+rr,0.f);
      }
    }
  }
}

extern "C" void kernel_launch(void* const* d_in, const int* in_sizes, int n_in,
                              void* d_out, int out_size, void* d_ws, size_t ws_size,
                              hipStream_t stream){
  const float* agts     = (const float*)d_in[0];
  const float* ctx      = (const float*)d_in[1];
  const float* agt_ctrs = (const float*)d_in[2];
  const float* ctx_ctrs = (const float*)d_in[3];
  const float* W_dist1  = (const float*)d_in[4];
  const float* b_dist1  = (const float*)d_in[5];
  const float* W_dist2  = (const float*)d_in[6];
  const float* g_dist   = (const float*)d_in[7];
  const float* b_dist   = (const float*)d_in[8];
  const float* W_q      = (const float*)d_in[9];
  const float* g_q      = (const float*)d_in[10];
  const float* b_q      = (const float*)d_in[11];
  const float* W_c1     = (const float*)d_in[12];
  const float* g_c1     = (const float*)d_in[13];
  const float* b_c1     = (const float*)d_in[14];
  const float* W_c2     = (const float*)d_in[15];
  const float* W_agt    = (const float*)d_in[16];
  const float* g_n      = (const float*)d_in[17];
  const float* b_n      = (const float*)d_in[18];
  const float* W_lin    = (const float*)d_in[19];
  const float* g_lin    = (const float*)d_in[20];
  const float* b_lin    = (const float*)d_in[21];
  const int*   hi       = (const int*)d_in[22];
  const int*   wi       = (const int*)d_in[23];

  int nA = in_sizes[0]/DD, nC = in_sizes[1]/DD, nE = in_sizes[22];
  float* out = (float*)d_out;

  auto al = [](size_t x){ return (x + 255) & ~(size_t)255; };
  size_t oAq2 = 0;
  size_t oCc  = al(oAq2 + (size_t)nA*DD*2);
  size_t oWp  = al(oCc  + (size_t)nC*DD*2);
  size_t oCnt = al(oWp  + (size_t)8*16384*2);
  size_t oPerm= al(oCnt + (size_t)nA*4);
  size_t oTail= al(oPerm+ (size_t)nA*CAP*4);
  size_t needA = oTail + (size_t)nE*DD*2;   // edge_out
  bool bigA = (ws_size >= needA);

  char* ws = (char*)d_ws;
  __bf16* Aq2bf = (__bf16*)(ws + oAq2);
  __bf16* Ccbf  = (__bf16*)(ws + oCc);
  __bf16* Wp    = (__bf16*)(ws + oWp);
  int*    counts= (int*)   (ws + oCnt);
  int*    perm  = (int*)   (ws + oPerm);
  __bf16* edge_out = (__bf16*)(ws + oTail);
  float*  CF    = (float*)(ws + oCnt);      // path-B only (aliases counts/perm region)

  dim3 B(256), B2(512);
  int gA2=(nA+127)/128, gC2=(nC+127)/128, gA=(nA+63)/64, gE=(nE+127)/128;
  int gBucket = bigA ? (nE+511)/512 : 0;

  // pack: 0=W_dist2 1=W_c1lo 2=W_c2 3=W_q 4=W_c1mid 5=W_c1hi 6=W_agt 7=W_lin
  pack_w<<<64,B,0,stream>>>(W_dist2, W_c1, W_c2, W_q,
                            W_c1+128*DD, W_c1+256*DD, W_agt, W_lin, Wp);
  if (bigA){
    hipMemsetAsync(counts, 0, (size_t)nA*4, stream);
    prep_kernel<<<gBucket+gA2+gC2,B2,0,stream>>>(hi, nE, counts, perm,
        agts, Wp+3*16384, g_q, b_q, Wp+4*16384, Wp+6*16384, Aq2bf, nullptr, nA,
        ctx, Wp+5*16384, Ccbf, nC, gBucket, gA2);
    edge_kernel<<<gE,B2,0,stream>>>(agt_ctrs, ctx_ctrs, hi, wi,
        W_dist1, b_dist1, Wp+0, g_dist, b_dist,
        Wp+1*16384, g_c1, b_c1, Wp+2*16384,
        Aq2bf, Ccbf, nullptr, edge_out, nE);
    final_fused<<<gA,B,0,stream>>>(agts, Wp+6*16384, counts, perm, edge_out,
        g_n, b_n, Wp+7*16384, g_lin, b_lin, out, nA);
  } else {
    prep_kernel<<<gA2+gC2,B2,0,stream>>>(hi, nE, counts, perm,
        agts, Wp+3*16384, g_q, b_q, Wp+4*16384, Wp+6*16384, Aq2bf, CF, nA,
        ctx, Wp+5*16384, Ccbf, nC, 0, gA2);
    edge_kernel<<<gE,B2,0,stream>>>(agt_ctrs, ctx_ctrs, hi, wi,
        W_dist1, b_dist1, Wp+0, g_dist, b_dist,
        Wp+1*16384, g_c1, b_c1, Wp+2*16384,
        Aq2bf, Ccbf, CF, nullptr, nE);
    final_kernel<<<gA,B,0,stream>>>(CF, g_n, b_n, Wp+7*16384, g_lin, b_lin, agts, out, nA);
  }
}